// Round 3
// baseline (1447.780 us; speedup 1.0000x reference)
//
#include <hip/hip_runtime.h>

#define BATCH 32768
#define NVEC  4096
#define EDIM  256
#define KNN   20

#define TS 128     // sample tile
#define TR 128     // codebook-row tile
#define TK 16      // K slab
#define PAD 20     // floats per LDS row (16 data + 4 pad, 16B aligned)

// monotone float -> uint encoding: order-preserving for all finite floats
__device__ __forceinline__ unsigned int fenc(float f) {
  unsigned int u = __float_as_uint(f);
  return (u & 0x80000000u) ? ~u : (u | 0x80000000u);
}

__global__ __launch_bounds__(256)
void k_init(unsigned long long* __restrict__ gkeys) {
  int i = blockIdx.x * 256 + threadIdx.x;
  if (i < BATCH) gkeys[i] = 0xFFFFFFFFFFFFFFFFull;
}

// exact fp32 dist[b][n] = sum_k x[b][k] * W[n][k]; per-sample argmin via
// (fenc(val) << 32 | idx) atomicMin — min value, tie -> smallest index (np).
__global__ __launch_bounds__(256)
void k_argmin_exact(const float* __restrict__ x, const float* __restrict__ W,
                    unsigned long long* __restrict__ gkeys) {
  __shared__ float xs[TS * PAD];
  __shared__ float wsh[TR * PAD];
  __shared__ unsigned long long kmin[TS];

  const int t  = threadIdx.x;
  const int sg = t & 15;    // sample group: samples sg*8 .. +7
  const int rg = t >> 4;    // row group:    rows    rg*8 .. +7
  const int m0 = blockIdx.x * TS;
  const int r0 = blockIdx.y * TR;

  if (t < TS) kmin[t] = 0xFFFFFFFFFFFFFFFFull;

  float acc[8][8];
  #pragma unroll
  for (int i = 0; i < 8; i++)
    #pragma unroll
    for (int j = 0; j < 8; j++) acc[i][j] = 0.f;

  // staging assignment: thread covers row sr (of both tiles), half hh
  const int sr = t >> 1, hh = t & 1;
  const float* gx = x + (size_t)(m0 + sr) * EDIM + hh * 8;
  const float* gw = W + (size_t)(r0 + sr) * EDIM + hh * 8;
  float* lx = xs  + sr * PAD + hh * 8;
  float* lw = wsh + sr * PAD + hh * 8;

  for (int kc = 0; kc < EDIM / TK; kc++) {
    __syncthreads();   // previous iter's frag reads done before overwrite
    float4 a0 = *(const float4*)(gx + kc * TK);
    float4 a1 = *(const float4*)(gx + kc * TK + 4);
    float4 b0 = *(const float4*)(gw + kc * TK);
    float4 b1 = *(const float4*)(gw + kc * TK + 4);
    *(float4*)lx = a0; *(float4*)(lx + 4) = a1;
    *(float4*)lw = b0; *(float4*)(lw + 4) = b1;
    __syncthreads();   // slab visible
    #pragma unroll
    for (int kq = 0; kq < 4; kq++) {
      float4 xa[8], wa[8];
      #pragma unroll
      for (int i = 0; i < 8; i++)
        xa[i] = *(const float4*)&xs[(sg * 8 + i) * PAD + kq * 4];
      #pragma unroll
      for (int j = 0; j < 8; j++)
        wa[j] = *(const float4*)&wsh[(rg * 8 + j) * PAD + kq * 4];
      #pragma unroll
      for (int i = 0; i < 8; i++)
        #pragma unroll
        for (int j = 0; j < 8; j++) {
          // k-sequential accumulation (matches naive np order class)
          acc[i][j] += xa[i].x * wa[j].x;
          acc[i][j] += xa[i].y * wa[j].y;
          acc[i][j] += xa[i].z * wa[j].z;
          acc[i][j] += xa[i].w * wa[j].w;
        }
    }
  }

  // per-thread: best row among its 8; ties -> smallest j (strict <)
  #pragma unroll
  for (int i = 0; i < 8; i++) {
    float bv = acc[i][0]; int bj = 0;
    #pragma unroll
    for (int j = 1; j < 8; j++)
      if (acc[i][j] < bv) { bv = acc[i][j]; bj = j; }
    unsigned long long key =
        ((unsigned long long)fenc(bv) << 32) | (unsigned)(r0 + rg * 8 + bj);
    atomicMin(&kmin[sg * 8 + i], key);
  }
  __syncthreads();
  if (t < TS) atomicMin(&gkeys[m0 + t], kmin[t]);
}

__global__ __launch_bounds__(256)
void k_out(const float* __restrict__ W, const unsigned long long* __restrict__ gkeys,
           float* __restrict__ out) {
  int b = blockIdx.x;
  int t = threadIdx.x;
  int ix = (int)(unsigned int)(gkeys[b] & 0xFFFFFFFFull);
  __shared__ float wt[41];
  __shared__ float invs;
  if (t < 41) {
    int d = t - KNN;
    int idx = ix + d;
    bool left  = (ix - KNN) < 0;
    bool valid = (idx >= 0) && (idx < NVEC) && (!left || (d < KNN));
    wt[t] = valid ? expf(-0.5f * (float)(d * d)) : 0.f;
  }
  __syncthreads();
  if (t == 0) {
    float ssum = 0.f;
    for (int i = 0; i < 41; i++) ssum += wt[i];
    invs = 1.f / ssum;
  }
  __syncthreads();
  float inv = invs;
  float a = 0.f;
  #pragma unroll
  for (int d = 0; d < 41; d++) {
    int idx = ix + d - KNN;
    idx = idx < 0 ? 0 : (idx >= NVEC ? NVEC - 1 : idx);
    a += wt[d] * W[(size_t)idx * EDIM + t];
  }
  out[(size_t)b * EDIM + t] = a * inv;
}

extern "C" void kernel_launch(void* const* d_in, const int* in_sizes, int n_in,
                              void* d_out, int out_size, void* d_ws, size_t ws_size,
                              hipStream_t stream) {
  const float* x = (const float*)d_in[0];   // [32768,256] fp32
  const float* W = (const float*)d_in[1];   // [4096,256]  fp32
  float* out = (float*)d_out;

  unsigned long long* gkeys = (unsigned long long*)d_ws;   // 256 KB

  k_init<<<(BATCH + 255) / 256, 256, 0, stream>>>(gkeys);
  dim3 grid(BATCH / TS, NVEC / TR);
  k_argmin_exact<<<grid, 256, 0, stream>>>(x, W, gkeys);
  k_out<<<BATCH, 256, 0, stream>>>(W, gkeys, out);
}

// Round 5
// 735.622 us; speedup vs baseline: 1.9681x; 1.9681x over previous
//
#include <hip/hip_runtime.h>

#define BATCH 32768
#define NVEC  4096
#define EDIM  256
#define KNN   20

#define BM 64            // samples per block
#define BN 256           // codebook rows per N-chunk
#define BK 32            // K depth per stage
#define NTHREADS 256     // 4 waves
#define NCHUNK (NVEC / BN)   // 16
#define NSTAGE (EDIM / BK)   // 8
#define CAP 16           // candidate capacity per sample
#define MARGIN 2.0f      // > 2 * worst-case bf16 dot error (~0.4 realistic)

typedef short          s16x8 __attribute__((ext_vector_type(8)));
typedef unsigned short u16x8 __attribute__((ext_vector_type(8)));
typedef float          f32x4 __attribute__((ext_vector_type(4)));

__device__ __forceinline__ void gload16(const void* g, void* l) {
  __builtin_amdgcn_global_load_lds(
      (const __attribute__((address_space(1))) unsigned int*)g,
      (__attribute__((address_space(3))) unsigned int*)l,
      16, 0, 0);
}

__device__ __forceinline__ unsigned short f2bf(float f) {
  unsigned int u = __float_as_uint(f);
  u += 0x7fffu + ((u >> 16) & 1u);   // RNE; inputs finite
  return (unsigned short)(u >> 16);
}

// monotone float<->uint encoding: order-preserving over all finite floats
__device__ __forceinline__ unsigned int fenc(float f) {
  unsigned int u = __float_as_uint(f);
  return (u & 0x80000000u) ? ~u : (u | 0x80000000u);
}
__device__ __forceinline__ float fdec(unsigned int e) {
  unsigned int u = (e & 0x80000000u) ? (e ^ 0x80000000u) : ~e;
  return __uint_as_float(u);
}

// fp32 k-ascending dot — EXACT source pattern of round-3's passing kernel
// (same compiler contraction => same rounding class as the np reference).
__device__ __forceinline__ float dot_np(const float4* __restrict__ xq,
                                        const float4* __restrict__ wq) {
  float d = 0.f;
  for (int k = 0; k < EDIM / 4; k++) {
    float4 a4 = xq[k], b4 = wq[k];
    d += a4.x * b4.x;
    d += a4.y * b4.y;
    d += a4.z * b4.z;
    d += a4.w * b4.w;
  }
  return d;
}

__global__ __launch_bounds__(256)
void k_convert_w(const float* __restrict__ W, unsigned short* __restrict__ Wb) {
  int i = blockIdx.x * 256 + threadIdx.x;   // 262144 float4 groups
  float4 v = ((const float4*)W)[i];
  ushort4 o; o.x = f2bf(v.x); o.y = f2bf(v.y); o.z = f2bf(v.z); o.w = f2bf(v.w);
  ((ushort4*)Wb)[i] = o;
}

// dist[n][m] = sum_k W[n][k]*x[m][k].  A = W rows (M dim), B = x samples (N dim).
__global__ __launch_bounds__(NTHREADS, 2)
void k_gemm_argmin(const float* __restrict__ x, const float* __restrict__ W,
                   const unsigned short* __restrict__ Wb,
                   int* __restrict__ ixo, int* __restrict__ cidx) {
  __shared__ unsigned short wbuf[2][BN * BK];   // 2 x 16 KB
  __shared__ unsigned int rowmin_enc[BM];
  __shared__ int          rowcnt[BM];
  __shared__ int          sh_bad;

  const int t    = threadIdx.x;
  const int lane = t & 63;
  const int wv   = t >> 6;       // 0..3: codebook quarter of each 256-chunk
  const int lm   = lane & 15;
  const int lq   = lane >> 4;
  const int m0   = blockIdx.x * BM;

  if (t < BM) { rowmin_enc[t] = 0xFFFFFFFFu; rowcnt[t] = 0; }
  if (t == 0) sh_bad = 0;

  // ---- x fragments: fp32 global -> RNE bf16 -> registers (B-operand layout) ----
  s16x8 xf[NSTAGE][4];
  #pragma unroll
  for (int j = 0; j < 4; j++) {
    const float* xp = x + (size_t)(m0 + j * 16 + lm) * EDIM + lq * 8;
    #pragma unroll
    for (int s = 0; s < NSTAGE; s++) {
      float4 v0 = *(const float4*)(xp + s * BK);
      float4 v1 = *(const float4*)(xp + s * BK + 4);
      u16x8 u;
      u[0] = f2bf(v0.x); u[1] = f2bf(v0.y); u[2] = f2bf(v0.z); u[3] = f2bf(v0.w);
      u[4] = f2bf(v1.x); u[5] = f2bf(v1.y); u[6] = f2bf(v1.z); u[7] = f2bf(v1.w);
      xf[s][j] = __builtin_bit_cast(s16x8, u);
    }
  }

  // stage one (nc, s) W slab: 256 rows x 32 bf16 = 16 KB, 4 rounds x 4 KB
  auto stage_w = [&](int nc, int s, unsigned short* dst) {
    const char* gw = (const char*)Wb + (size_t)nc * (BN * EDIM * 2) + s * (BK * 2);
    #pragma unroll
    for (int rnd = 0; rnd < 4; rnd++) {
      int fw  = rnd * 4096 + wv * 1024;   // wave-uniform LDS byte base
      int f   = fw + lane * 16;
      int row = f >> 6;                   // 64 B per LDS row (32 bf16)
      int inr = f & 63;
      gload16(gw + (size_t)row * (EDIM * 2) + inr, (char*)dst + fw);
    }
  };

  stage_w(0, 0, wbuf[0]);

  const int abase = (wv * 64 + lm) * BK + lq * 8;   // W-lds ushort index base
  const f32x4 fz = {0.f, 0.f, 0.f, 0.f};

  for (int nc = 0; nc < NCHUNK; nc++) {
    f32x4 acc[4][4];
    #pragma unroll
    for (int i = 0; i < 4; i++)
      #pragma unroll
      for (int j = 0; j < 4; j++) acc[i][j] = fz;

    #pragma unroll
    for (int s = 0; s < NSTAGE; s++) {
      __syncthreads();   // staged (nc,s) complete (barrier drains vmcnt)
      int ns = s + 1, nnc = nc;
      if (ns == NSTAGE) { ns = 0; nnc++; }
      if (nnc < NCHUNK) stage_w(nnc, ns, wbuf[(s + 1) & 1]);
      const unsigned short* cw = wbuf[s & 1];
      s16x8 a[4];
      #pragma unroll
      for (int i = 0; i < 4; i++)
        a[i] = *(const s16x8*)(cw + abase + i * (16 * BK));
      #pragma unroll
      for (int i = 0; i < 4; i++)
        #pragma unroll
        for (int j = 0; j < 4; j++)
          acc[i][j] = __builtin_amdgcn_mfma_f32_16x16x32_bf16(a[i], xf[s][j], acc[i][j], 0, 0, 0);
    }

    // ---- per-sample running min (merged across waves) ----
    #pragma unroll
    for (int j = 0; j < 4; j++) {
      float m = acc[0][j][0];
      #pragma unroll
      for (int i = 0; i < 4; i++)
        #pragma unroll
        for (int r = 0; r < 4; r++) m = fminf(m, acc[i][j][r]);
      m = fminf(m, __shfl_xor(m, 16));
      m = fminf(m, __shfl_xor(m, 32));
      if (lq == 0) atomicMin(&rowmin_enc[j * 16 + lm], fenc(m));
    }
    __syncthreads();

    // ---- layout self-check (last chunk): one exact dot per thread ----
    if (nc == NCHUNK - 1) {
      int n_chk = (NCHUNK - 1) * BN + wv * 64 + lq * 4;   // i=0, r=0
      int s_chk = m0 + lm;                                 // j=0
      float ex = dot_np((const float4*)(x + (size_t)s_chk * EDIM),
                        (const float4*)(W + (size_t)n_chk * EDIM));
      if (fabsf(ex - acc[0][0][0]) > 2.0f) sh_bad = 1;
    }

    // ---- candidate capture (indices only; values recomputed in refine) ----
    #pragma unroll
    for (int j = 0; j < 4; j++) {
      int sl = j * 16 + lm;
      float th = fdec(rowmin_enc[sl]) + MARGIN;
      #pragma unroll
      for (int i = 0; i < 4; i++)
        #pragma unroll
        for (int r = 0; r < 4; r++) {
          if (acc[i][j][r] <= th) {
            int n = nc * BN + wv * 64 + i * 16 + lq * 4 + r;
            int slot = atomicAdd(&rowcnt[sl], 1);
            if (slot < CAP) cidx[(size_t)(m0 + sl) * CAP + slot] = n;
          }
        }
    }
  }

  __threadfence_block();
  __syncthreads();

  // ---- refine: np-order fp32 dots; min value, tie -> smallest index ----
  const bool bad = (sh_bad != 0);
  for (int rr = 0; rr < 16; rr++) {
    int row = wv * 16 + rr;
    int b = m0 + row;
    int c = rowcnt[row];
    bool ovf = bad || (c > CAP);
    if (c > CAP) c = CAP;
    const float4* xq = (const float4*)(x + (size_t)b * EDIM);
    unsigned long long bestkey = 0xFFFFFFFFFFFFFFFFull;
    if (!ovf) {
      if (lane < c) {
        int n = cidx[(size_t)b * CAP + lane];
        float d = dot_np(xq, (const float4*)(W + (size_t)n * EDIM));
        bestkey = ((unsigned long long)fenc(d) << 32) | (unsigned)n;
      }
    } else {
      // fallback (layout-bad or capture overflow): full scan, np-order fp32
      for (int n = lane; n < NVEC; n += 64) {
        float d = dot_np(xq, (const float4*)(W + (size_t)n * EDIM));
        unsigned long long key = ((unsigned long long)fenc(d) << 32) | (unsigned)n;
        if (key < bestkey) bestkey = key;
      }
    }
    #pragma unroll
    for (int off = 32; off >= 1; off >>= 1) {
      unsigned long long o = __shfl_xor(bestkey, off);
      if (o < bestkey) bestkey = o;
    }
    if (lane == 0) ixo[b] = (int)(unsigned int)(bestkey & 0xFFFFFFFFull);
  }
}

__global__ __launch_bounds__(256)
void k_out(const float* __restrict__ W, const int* __restrict__ ixo,
           float* __restrict__ out) {
  int b = blockIdx.x;
  int t = threadIdx.x;
  int ix = ixo[b];
  __shared__ float wt[41];
  __shared__ float invs;
  if (t < 41) {
    int d = t - KNN;
    int idx = ix + d;
    bool left  = (ix - KNN) < 0;
    bool valid = (idx >= 0) && (idx < NVEC) && (!left || (d < KNN));
    wt[t] = valid ? expf(-0.5f * (float)(d * d)) : 0.f;
  }
  __syncthreads();
  if (t == 0) {
    float ssum = 0.f;
    for (int i = 0; i < 41; i++) ssum += wt[i];
    invs = 1.f / ssum;
  }
  __syncthreads();
  float inv = invs;
  float a = 0.f;
  #pragma unroll
  for (int d = 0; d < 41; d++) {
    int idx = ix + d - KNN;
    idx = idx < 0 ? 0 : (idx >= NVEC ? NVEC - 1 : idx);
    a += wt[d] * W[(size_t)idx * EDIM + t];
  }
  out[(size_t)b * EDIM + t] = a * inv;
}

extern "C" void kernel_launch(void* const* d_in, const int* in_sizes, int n_in,
                              void* d_out, int out_size, void* d_ws, size_t ws_size,
                              hipStream_t stream) {
  const float* x = (const float*)d_in[0];   // [32768,256] fp32
  const float* W = (const float*)d_in[1];   // [4096,256]  fp32
  float* out = (float*)d_out;

  char* ws = (char*)d_ws;
  unsigned short* Wb = (unsigned short*)ws;                       // 2 MB
  char* p = ws + (size_t)NVEC * EDIM * 2;
  int*   ixo  = (int*)p;   p += (size_t)BATCH * 4;                // 128 KB
  int*   cidx = (int*)p;                                          // 2 MB

  k_convert_w<<<NVEC * EDIM / 4 / 256, 256, 0, stream>>>(W, Wb);
  k_gemm_argmin<<<BATCH / BM, NTHREADS, 0, stream>>>(x, W, Wb, ixo, cidx);
  k_out<<<BATCH, 256, 0, stream>>>(W, ixo, out);
}

// Round 6
// 465.419 us; speedup vs baseline: 3.1107x; 1.5806x over previous
//
#include <hip/hip_runtime.h>

#define BATCH 32768
#define NVEC  4096
#define EDIM  256
#define KNN   20

#define BM 64            // samples per block
#define BN 256           // codebook rows per N-chunk
#define NTHREADS 256     // 4 waves
#define NCHUNK (NVEC / BN)   // 16
#define CAP 64           // candidate capacity per sample (E[captures]~16-32)
#define MARGIN 2.0f      // > 2 * worst-case bf16 dot error (~0.64)

typedef short          s16x8 __attribute__((ext_vector_type(8)));
typedef unsigned short u16x8 __attribute__((ext_vector_type(8)));
typedef float          f32x4 __attribute__((ext_vector_type(4)));

__device__ __forceinline__ unsigned short f2bf(float f) {
  unsigned int u = __float_as_uint(f);
  u += 0x7fffu + ((u >> 16) & 1u);   // RNE; inputs finite
  return (unsigned short)(u >> 16);
}

// monotone float<->uint encoding: order-preserving over all finite floats
__device__ __forceinline__ unsigned int fenc(float f) {
  unsigned int u = __float_as_uint(f);
  return (u & 0x80000000u) ? ~u : (u | 0x80000000u);
}
__device__ __forceinline__ float fdec(unsigned int e) {
  unsigned int u = (e & 0x80000000u) ? (e ^ 0x80000000u) : ~e;
  return __uint_as_float(u);
}

// fp32 k-ascending dot — EXACT source pattern of round-3's passing kernel
// (same compiler contraction => same rounding class as the np reference).
__device__ __forceinline__ float dot_np(const float4* __restrict__ xq,
                                        const float4* __restrict__ wq) {
  float d = 0.f;
  for (int k = 0; k < EDIM / 4; k++) {
    float4 a4 = xq[k], b4 = wq[k];
    d += a4.x * b4.x;
    d += a4.y * b4.y;
    d += a4.z * b4.z;
    d += a4.w * b4.w;
  }
  return d;
}

__global__ __launch_bounds__(256)
void k_convert_w(const float* __restrict__ W, unsigned short* __restrict__ Wb) {
  int i = blockIdx.x * 256 + threadIdx.x;   // 262144 float4 groups
  float4 v = ((const float4*)W)[i];
  ushort4 o; o.x = f2bf(v.x); o.y = f2bf(v.y); o.z = f2bf(v.z); o.w = f2bf(v.w);
  ((ushort4*)Wb)[i] = o;
}

// dist[n][m] = sum_k W[n][k]*x[m][k].  A = W rows (M dim), B = x samples (N dim).
// W streams L2 -> registers directly; no LDS tile, no K-loop barriers.
__global__ __launch_bounds__(NTHREADS, 2)
void k_gemm_argmin(const float* __restrict__ x, const float* __restrict__ W,
                   const unsigned short* __restrict__ Wb,
                   int* __restrict__ ixo,
                   int* __restrict__ cidx, float* __restrict__ cval) {
  __shared__ unsigned int rowmin_enc[BM];
  __shared__ int          rowcnt[BM];
  __shared__ int          sh_bad;

  const int t    = threadIdx.x;
  const int lane = t & 63;
  const int wv   = t >> 6;       // 0..3: codebook quarter of each 256-chunk
  const int lm   = lane & 15;
  const int lq   = lane >> 4;
  const int m0   = blockIdx.x * BM;

  if (t < BM) { rowmin_enc[t] = 0xFFFFFFFFu; rowcnt[t] = 0; }
  if (t == 0) sh_bad = 0;

  // ---- x fragments: fp32 global -> RNE bf16 -> registers (B-operand layout) ----
  s16x8 xf[8][4];
  #pragma unroll
  for (int j = 0; j < 4; j++) {
    const float* xp = x + (size_t)(m0 + j * 16 + lm) * EDIM + lq * 8;
    #pragma unroll
    for (int s = 0; s < 8; s++) {
      float4 v0 = *(const float4*)(xp + s * 32);
      float4 v1 = *(const float4*)(xp + s * 32 + 4);
      u16x8 u;
      u[0] = f2bf(v0.x); u[1] = f2bf(v0.y); u[2] = f2bf(v0.z); u[3] = f2bf(v0.w);
      u[4] = f2bf(v1.x); u[5] = f2bf(v1.y); u[6] = f2bf(v1.z); u[7] = f2bf(v1.w);
      xf[s][j] = __builtin_bit_cast(s16x8, u);
    }
  }
  __syncthreads();   // shared init visible

  // per-lane W base: row (wv*64 + lm), k-block lq*8   [A-operand layout]
  const unsigned short* wbase = Wb + (size_t)(wv * 64 + lm) * EDIM + lq * 8;
  const f32x4 fz = {0.f, 0.f, 0.f, 0.f};

  for (int nc = 0; nc < NCHUNK; nc++) {
    f32x4 acc[4][4];
    #pragma unroll
    for (int i = 0; i < 4; i++)
      #pragma unroll
      for (int j = 0; j < 4; j++) acc[i][j] = fz;

    const unsigned short* wc = wbase + (size_t)nc * (BN * EDIM);
    #pragma unroll
    for (int s = 0; s < 8; s++) {
      s16x8 a[4];
      #pragma unroll
      for (int i = 0; i < 4; i++)
        a[i] = *(const s16x8*)(wc + i * (16 * EDIM) + s * 32);
      #pragma unroll
      for (int i = 0; i < 4; i++)
        #pragma unroll
        for (int j = 0; j < 4; j++)
          acc[i][j] = __builtin_amdgcn_mfma_f32_16x16x32_bf16(a[i], xf[s][j], acc[i][j], 0, 0, 0);
    }

    // ---- per-sample running min (merged across waves) ----
    #pragma unroll
    for (int j = 0; j < 4; j++) {
      float m = acc[0][j][0];
      #pragma unroll
      for (int i = 0; i < 4; i++)
        #pragma unroll
        for (int r = 0; r < 4; r++) m = fminf(m, acc[i][j][r]);
      m = fminf(m, __shfl_xor(m, 16));
      m = fminf(m, __shfl_xor(m, 32));
      if (lq == 0) atomicMin(&rowmin_enc[j * 16 + lm], fenc(m));
    }
    __syncthreads();

    // ---- layout self-check (last chunk): one exact dot per thread ----
    if (nc == NCHUNK - 1) {
      int n_chk = (NCHUNK - 1) * BN + wv * 64 + lq * 4;   // i=0, r=0
      int s_chk = m0 + lm;                                 // j=0
      float ex = dot_np((const float4*)(x + (size_t)s_chk * EDIM),
                        (const float4*)(W + (size_t)n_chk * EDIM));
      if (fabsf(ex - acc[0][0][0]) > 2.0f) sh_bad = 1;
    }

    // ---- candidate capture (store value too; refine filters by final min) ----
    #pragma unroll
    for (int j = 0; j < 4; j++) {
      int sl = j * 16 + lm;
      float th = fdec(rowmin_enc[sl]) + MARGIN;
      #pragma unroll
      for (int i = 0; i < 4; i++)
        #pragma unroll
        for (int r = 0; r < 4; r++) {
          float v = acc[i][j][r];
          if (v <= th) {
            int n = nc * BN + wv * 64 + i * 16 + lq * 4 + r;
            int slot = atomicAdd(&rowcnt[sl], 1);
            if (slot < CAP) {
              size_t o = (size_t)(m0 + sl) * CAP + slot;
              cidx[o] = n; cval[o] = v;
            }
          }
        }
    }
    __syncthreads();   // capture done before next chunk's rowmin updates
  }

  __threadfence_block();

  // ---- refine: np-order fp32 dots over final-margin survivors ----
  const bool bad = (sh_bad != 0);
  for (int rr = 0; rr < 16; rr++) {
    int row = wv * 16 + rr;
    int b = m0 + row;
    int c = rowcnt[row];
    bool ovf = bad || (c > CAP);
    if (c > CAP) c = CAP;
    float vfin = fdec(rowmin_enc[row]) + MARGIN;   // final bf16 min + margin
    const float4* xq = (const float4*)(x + (size_t)b * EDIM);
    unsigned long long bestkey = 0xFFFFFFFFFFFFFFFFull;
    if (!ovf) {
      int n = 0; bool act = false;
      if (lane < c) {
        size_t o = (size_t)b * CAP + lane;
        n = cidx[o]; act = (cval[o] <= vfin);
      }
      if (act) {
        float d = dot_np(xq, (const float4*)(W + (size_t)n * EDIM));
        bestkey = ((unsigned long long)fenc(d) << 32) | (unsigned)n;
      }
    } else {
      // fallback (layout-bad or capture overflow): full scan, np-order fp32
      for (int n = lane; n < NVEC; n += 64) {
        float d = dot_np(xq, (const float4*)(W + (size_t)n * EDIM));
        unsigned long long key = ((unsigned long long)fenc(d) << 32) | (unsigned)n;
        if (key < bestkey) bestkey = key;
      }
    }
    #pragma unroll
    for (int off = 32; off >= 1; off >>= 1) {
      unsigned long long o = __shfl_xor(bestkey, off);
      if (o < bestkey) bestkey = o;
    }
    if (lane == 0) ixo[b] = (int)(unsigned int)(bestkey & 0xFFFFFFFFull);
  }
}

// one sample per wave: weights in lanes 0..40, shfl-broadcast, float4 gathers
__global__ __launch_bounds__(256)
void k_out(const float* __restrict__ W, const int* __restrict__ ixo,
           float* __restrict__ out) {
  int lane = threadIdx.x & 63;
  int b = blockIdx.x * 4 + (threadIdx.x >> 6);
  int ix = ixo[b];
  float w = 0.f;
  if (lane < 41) {
    int d = lane - KNN;
    int idx = ix + d;
    bool left  = (ix - KNN) < 0;
    bool valid = (idx >= 0) && (idx < NVEC) && (!left || (d < KNN));
    w = valid ? expf(-0.5f * (float)(d * d)) : 0.f;
  }
  float ssum = w;
  #pragma unroll
  for (int off = 32; off >= 1; off >>= 1) ssum += __shfl_xor(ssum, off);
  float inv = 1.f / ssum;

  float4 acc = {0.f, 0.f, 0.f, 0.f};
  #pragma unroll
  for (int d = 0; d < 41; d++) {
    float wd = __shfl(w, d);
    int idx = ix + d - KNN;
    idx = idx < 0 ? 0 : (idx >= NVEC ? NVEC - 1 : idx);
    float4 wr = *(const float4*)(W + (size_t)idx * EDIM + lane * 4);
    acc.x += wd * wr.x; acc.y += wd * wr.y;
    acc.z += wd * wr.z; acc.w += wd * wr.w;
  }
  acc.x *= inv; acc.y *= inv; acc.z *= inv; acc.w *= inv;
  *(float4*)(out + (size_t)b * EDIM + lane * 4) = acc;
}

extern "C" void kernel_launch(void* const* d_in, const int* in_sizes, int n_in,
                              void* d_out, int out_size, void* d_ws, size_t ws_size,
                              hipStream_t stream) {
  const float* x = (const float*)d_in[0];   // [32768,256] fp32
  const float* W = (const float*)d_in[1];   // [4096,256]  fp32
  float* out = (float*)d_out;

  char* ws = (char*)d_ws;
  unsigned short* Wb = (unsigned short*)ws;                       // 2 MB
  char* p = ws + (size_t)NVEC * EDIM * 2;
  int*   ixo  = (int*)p;   p += (size_t)BATCH * 4;                // 128 KB
  int*   cidx = (int*)p;   p += (size_t)BATCH * CAP * 4;          // 8 MB
  float* cval = (float*)p;                                        // 8 MB

  k_convert_w<<<NVEC * EDIM / 4 / 256, 256, 0, stream>>>(W, Wb);
  k_gemm_argmin<<<BATCH / BM, NTHREADS, 0, stream>>>(x, W, Wb, ixo, cidx, cval);
  k_out<<<BATCH / 4, 256, 0, stream>>>(W, ixo, out);
}

// Round 7
// 447.360 us; speedup vs baseline: 3.2363x; 1.0404x over previous
//
#include <hip/hip_runtime.h>

#define BATCH 32768
#define NVEC  4096
#define EDIM  256
#define KNN   20

#define BM 64            // samples per block
#define BNC 256          // codebook rows per chunk
#define BKS 32           // K depth per stage
#define NHALF 2048       // rows per block (N split in 2)
#define NTHREADS 256     // 4 waves
#define XPITCH 264       // x-LDS row pitch in ushorts (256 + 8 pad, 16B aligned)
#define CAP 64           // candidate capacity per sample
#define MARGIN 2.0f      // > 2 * worst-case bf16 dot error (~0.6)

typedef short          s16x8 __attribute__((ext_vector_type(8)));
typedef unsigned short u16x8 __attribute__((ext_vector_type(8)));
typedef float          f32x4 __attribute__((ext_vector_type(4)));

__device__ __forceinline__ void gload16(const void* g, void* l) {
  __builtin_amdgcn_global_load_lds(
      (const __attribute__((address_space(1))) unsigned int*)g,
      (__attribute__((address_space(3))) unsigned int*)l,
      16, 0, 0);
}

__device__ __forceinline__ unsigned short f2bf(float f) {
  unsigned int u = __float_as_uint(f);
  u += 0x7fffu + ((u >> 16) & 1u);   // RNE; inputs finite
  return (unsigned short)(u >> 16);
}

// monotone float<->uint encoding: order-preserving over all finite floats
__device__ __forceinline__ unsigned int fenc(float f) {
  unsigned int u = __float_as_uint(f);
  return (u & 0x80000000u) ? ~u : (u | 0x80000000u);
}
__device__ __forceinline__ float fdec(unsigned int e) {
  unsigned int u = (e & 0x80000000u) ? (e ^ 0x80000000u) : ~e;
  return __uint_as_float(u);
}

// fp32 k-ascending dot — EXACT source pattern of round-3's passing kernel
// (same compiler contraction => same rounding class as the np reference).
__device__ __forceinline__ float dot_np(const float4* __restrict__ xq,
                                        const float4* __restrict__ wq) {
  float d = 0.f;
  for (int k = 0; k < EDIM / 4; k++) {
    float4 a4 = xq[k], b4 = wq[k];
    d += a4.x * b4.x;
    d += a4.y * b4.y;
    d += a4.z * b4.z;
    d += a4.w * b4.w;
  }
  return d;
}

__global__ __launch_bounds__(256)
void k_convert_w(const float* __restrict__ W, unsigned short* __restrict__ Wb) {
  int i = blockIdx.x * 256 + threadIdx.x;   // 262144 float4 groups
  float4 v = ((const float4*)W)[i];
  ushort4 o; o.x = f2bf(v.x); o.y = f2bf(v.y); o.z = f2bf(v.z); o.w = f2bf(v.w);
  ((ushort4*)Wb)[i] = o;
}

// dist[n][m] = sum_k W[n][k]*x[m][k].  A = W rows (D rows), B = x samples (D cols).
// x tile in padded LDS; W staged per-stage via global_load_lds (m97 pattern).
__global__ __launch_bounds__(NTHREADS, 3)
void k_gemm_argmin(const float* __restrict__ x, const float* __restrict__ W,
                   const unsigned short* __restrict__ Wb,
                   unsigned int* __restrict__ grmin, int* __restrict__ growcnt,
                   int* __restrict__ cidx, float* __restrict__ cval) {
  __shared__ unsigned short xs[BM * XPITCH];      // 33792 B
  __shared__ unsigned short wbuf[BNC * BKS];      // 16384 B
  __shared__ unsigned int rowmin_enc[BM];

  const int t    = threadIdx.x;
  const int lane = t & 63;
  const int wv   = t >> 6;       // 0..3: 64-row strip of each 256-chunk
  const int lm   = lane & 15;
  const int lq   = lane >> 4;
  const int m0   = blockIdx.x * BM;
  const int nb0  = blockIdx.y * NHALF;   // this block's first codebook row

  if (t < BM) rowmin_enc[t] = 0xFFFFFFFFu;

  // ---- stage x tile: fp32 global -> RNE bf16 -> padded LDS ----
  {
    const int r = t >> 2, sg = t & 3;
    const float* xp = x + (size_t)(m0 + r) * EDIM + sg * 64;
    unsigned short* dst = xs + r * XPITCH + sg * 64;
    #pragma unroll
    for (int u = 0; u < 8; u++) {
      float4 v0 = *(const float4*)(xp + u * 8);
      float4 v1 = *(const float4*)(xp + u * 8 + 4);
      u16x8 uu;
      uu[0] = f2bf(v0.x); uu[1] = f2bf(v0.y); uu[2] = f2bf(v0.z); uu[3] = f2bf(v0.w);
      uu[4] = f2bf(v1.x); uu[5] = f2bf(v1.y); uu[6] = f2bf(v1.z); uu[7] = f2bf(v1.w);
      *(u16x8*)(dst + u * 8) = uu;
    }
  }
  __syncthreads();

  const int abase = (wv * 64 + lm) * BKS + lq * 8;   // W-lds ushort idx (i adds 16*BKS)
  const int bbase = lm * XPITCH + lq * 8;            // x-lds ushort idx (j adds 16*XPITCH)
  const f32x4 fz = {0.f, 0.f, 0.f, 0.f};

  for (int nc = 0; nc < NHALF / BNC; nc++) {
    const int nbase = nb0 + nc * BNC;
    f32x4 acc[4][4];
    #pragma unroll
    for (int i = 0; i < 4; i++)
      #pragma unroll
      for (int j = 0; j < 4; j++) acc[i][j] = fz;

    #pragma unroll
    for (int s = 0; s < EDIM / BKS; s++) {
      __syncthreads();   // prior stage's consumers done
      // stage W slab: 256 rows x 32 bf16 = 16 KB (4 x gload16 per thread)
      {
        const char* gw = (const char*)Wb + (size_t)nbase * (EDIM * 2) + s * (BKS * 2);
        int fw = wv * 1024;
        #pragma unroll
        for (int rnd = 0; rnd < 4; rnd++) {
          int f = fw + lane * 16;
          int row = f >> 6, inr = f & 63;
          gload16(gw + (size_t)row * (EDIM * 2) + inr, (char*)wbuf + fw);
          fw += 4096;
        }
      }
      __syncthreads();   // vmcnt drained -> slab visible
      s16x8 a[4], b[4];
      #pragma unroll
      for (int i = 0; i < 4; i++)
        a[i] = *(const s16x8*)(wbuf + abase + i * (16 * BKS));
      #pragma unroll
      for (int j = 0; j < 4; j++)
        b[j] = *(const s16x8*)(xs + bbase + j * (16 * XPITCH) + s * BKS);
      #pragma unroll
      for (int i = 0; i < 4; i++)
        #pragma unroll
        for (int j = 0; j < 4; j++)
          acc[i][j] = __builtin_amdgcn_mfma_f32_16x16x32_bf16(a[i], b[j], acc[i][j], 0, 0, 0);
    }

    // ---- per-sample running min (merged across waves, block-local) ----
    #pragma unroll
    for (int j = 0; j < 4; j++) {
      float m = acc[0][j][0];
      #pragma unroll
      for (int i = 0; i < 4; i++)
        #pragma unroll
        for (int r = 0; r < 4; r++) m = fminf(m, acc[i][j][r]);
      m = fminf(m, __shfl_xor(m, 16));
      m = fminf(m, __shfl_xor(m, 32));
      if (lq == 0) atomicMin(&rowmin_enc[j * 16 + lm], fenc(m));
    }
    __syncthreads();

    // ---- layout self-check (last local chunk): one exact dot per thread ----
    if (nc == NHALF / BNC - 1) {
      int n_chk = nbase + wv * 64 + lq * 4;   // i=0, r=0
      int s_chk = m0 + lm;                    // j=0
      float ex = dot_np((const float4*)(x + (size_t)s_chk * EDIM),
                        (const float4*)(W + (size_t)n_chk * EDIM));
      if (fabsf(ex - acc[0][0][0]) > 2.0f) atomicOr(growcnt + BATCH, 1);
    }

    // ---- candidate capture: threshold = local running min + margin ----
    #pragma unroll
    for (int j = 0; j < 4; j++) {
      int sl = j * 16 + lm;
      float th = fdec(rowmin_enc[sl]) + MARGIN;
      #pragma unroll
      for (int i = 0; i < 4; i++)
        #pragma unroll
        for (int r = 0; r < 4; r++) {
          float v = acc[i][j][r];
          if (v <= th) {
            int n = nbase + wv * 64 + i * 16 + lq * 4 + r;
            int slot = atomicAdd(&growcnt[m0 + sl], 1);
            if (slot < CAP) {
              size_t o = (size_t)(m0 + sl) * CAP + slot;
              cidx[o] = n; cval[o] = v;
            }
          }
        }
    }
  }

  // merge block-local minima into global per-sample min
  if (t < BM) atomicMin(&grmin[m0 + t], rowmin_enc[t]);
}

// fused refine (np-order fp32 argmin over survivors) + weighted-window output.
// one sample per wave.
__global__ __launch_bounds__(256)
void k_refine_out(const float* __restrict__ x, const float* __restrict__ W,
                  const unsigned int* __restrict__ grmin,
                  const int* __restrict__ growcnt,
                  const int* __restrict__ cidx, const float* __restrict__ cval,
                  float* __restrict__ out) {
  const int lane = threadIdx.x & 63;
  const int b = blockIdx.x * 4 + (threadIdx.x >> 6);

  const int bad = growcnt[BATCH];
  int c = growcnt[b];
  bool ovf = (bad != 0) || (c > CAP);
  if (c > CAP) c = CAP;
  const float vfin = fdec(grmin[b]) + MARGIN;
  const float4* xq = (const float4*)(x + (size_t)b * EDIM);

  unsigned long long bestkey = 0xFFFFFFFFFFFFFFFFull;
  if (!ovf) {
    int n = 0; bool act = false;
    if (lane < c) {
      size_t o = (size_t)b * CAP + lane;
      n = cidx[o]; act = (cval[o] <= vfin);
    }
    if (act) {
      float d = dot_np(xq, (const float4*)(W + (size_t)n * EDIM));
      bestkey = ((unsigned long long)fenc(d) << 32) | (unsigned)n;
    }
  } else {
    // fallback (layout-bad or capture overflow): full scan, np-order fp32
    for (int n = lane; n < NVEC; n += 64) {
      float d = dot_np(xq, (const float4*)(W + (size_t)n * EDIM));
      unsigned long long key = ((unsigned long long)fenc(d) << 32) | (unsigned)n;
      if (key < bestkey) bestkey = key;
    }
  }
  #pragma unroll
  for (int off = 32; off >= 1; off >>= 1) {
    unsigned long long o = __shfl_xor(bestkey, off);
    if (o < bestkey) bestkey = o;
  }
  const int ix = (int)(unsigned int)(bestkey & 0xFFFFFFFFull);

  // ---- weighted window output (reference's left-edge quirk included) ----
  float w = 0.f;
  if (lane < 41) {
    int d = lane - KNN;
    int idx = ix + d;
    bool left  = (ix - KNN) < 0;
    bool valid = (idx >= 0) && (idx < NVEC) && (!left || (d < KNN));
    w = valid ? expf(-0.5f * (float)(d * d)) : 0.f;
  }
  float ssum = w;
  #pragma unroll
  for (int off = 32; off >= 1; off >>= 1) ssum += __shfl_xor(ssum, off);
  float inv = 1.f / ssum;

  float4 acc = {0.f, 0.f, 0.f, 0.f};
  #pragma unroll
  for (int d = 0; d < 41; d++) {
    float wd = __shfl(w, d);
    int idx = ix + d - KNN;
    idx = idx < 0 ? 0 : (idx >= NVEC ? NVEC - 1 : idx);
    float4 wr = *(const float4*)(W + (size_t)idx * EDIM + lane * 4);
    acc.x += wd * wr.x; acc.y += wd * wr.y;
    acc.z += wd * wr.z; acc.w += wd * wr.w;
  }
  acc.x *= inv; acc.y *= inv; acc.z *= inv; acc.w *= inv;
  *(float4*)(out + (size_t)b * EDIM + lane * 4) = acc;
}

extern "C" void kernel_launch(void* const* d_in, const int* in_sizes, int n_in,
                              void* d_out, int out_size, void* d_ws, size_t ws_size,
                              hipStream_t stream) {
  const float* x = (const float*)d_in[0];   // [32768,256] fp32
  const float* W = (const float*)d_in[1];   // [4096,256]  fp32
  float* out = (float*)d_out;

  char* ws = (char*)d_ws;
  unsigned short* Wb   = (unsigned short*)ws;                     // 2 MB
  char* p = ws + (size_t)NVEC * EDIM * 2;
  unsigned int* grmin  = (unsigned int*)p;  p += (size_t)BATCH * 4;        // 128 KB
  int*          growcnt= (int*)p;           p += (size_t)(BATCH + 1) * 4;  // 128 KB + badflag
  int*          cidx   = (int*)p;           p += (size_t)BATCH * CAP * 4;  // 8 MB
  float*        cval   = (float*)p;                                        // 8 MB

  hipMemsetAsync(grmin, 0xFF, (size_t)BATCH * 4, stream);
  hipMemsetAsync(growcnt, 0, (size_t)(BATCH + 1) * 4, stream);

  k_convert_w<<<NVEC * EDIM / 4 / 256, 256, 0, stream>>>(W, Wb);
  dim3 grid(BATCH / BM, NVEC / NHALF);   // 512 x 2
  k_gemm_argmin<<<grid, NTHREADS, 0, stream>>>(x, W, Wb, grmin, growcnt, cidx, cval);
  k_refine_out<<<BATCH / 4, 256, 0, stream>>>(x, W, grmin, growcnt, cidx, cval, out);
}